// Round 4
// baseline (442.846 us; speedup 1.0000x reference)
//
#include <hip/hip_runtime.h>

#define NCLS 1024
#define DIM  256
#define NTOT 2048   // 2*NCLS rows in "total"
#define DSL  8      // D slices
#define DW   32     // dims per slice (128B per row -> full cache lines)
#define SMAX 16

// ---------------- init: zero the accumulators we atomically add into ----------
__global__ void k_init(int* counts, float* s, double* sumsq, double* lossacc){
  int t = threadIdx.x;
  if (t < NCLS) counts[t] = 0;
  if (t < DIM)  s[t] = 0.f;
  if (t == 0){ *sumsq = 0.0; *lossacc = 0.0; }
}

// ---------------- histogram of targets (LDS-staged) ---------------------------
__global__ __launch_bounds__(256) void k_hist(const int* __restrict__ tgt, int n,
                                              int* __restrict__ counts){
  __shared__ int h[NCLS];
  for (int i = threadIdx.x; i < NCLS; i += blockDim.x) h[i] = 0;
  __syncthreads();
  for (int i = blockIdx.x*blockDim.x + threadIdx.x; i < n; i += gridDim.x*blockDim.x)
    atomicAdd(&h[tgt[i]], 1);
  __syncthreads();
  for (int i = threadIdx.x; i < NCLS; i += blockDim.x)
    if (h[i]) atomicAdd(&counts[i], h[i]);
}

// ---------------- streaming partial segment-sum --------------------------------
// grid = 2 arrays x 8 dslices x S slabs, 1024 threads.
// Sequential reads (stride 1KB, 128B full-line chunks), LDS scatter with
// per-class bank rotation: slot(cls, w) = cls*32 + ((w + cls) & 31).
__global__ __launch_bounds__(1024) void k_partial(
    const float* __restrict__ xr, const float* __restrict__ xi,
    const int* __restrict__ tgt, int n, int S, int rows_per_slab,
    float* __restrict__ P)
{
  __shared__ float acc[NCLS*DW];   // 128 KB
  int bx = blockIdx.x;
  int sl = bx % S;
  int d  = (bx / S) % DSL;
  int a  = bx / (S*DSL);
  const float* __restrict__ X = a ? xi : xr;
  int tid = threadIdx.x;
  for (int i = tid; i < NCLS*DW; i += 1024) acc[i] = 0.f;
  __syncthreads();

  int r0 = sl * rows_per_slab;
  int r1 = r0 + rows_per_slab; if (r1 > n) r1 = n;
  int rg = tid >> 3;              // row slot 0..127
  int lg = tid & 7;               // quad-of-dims within slice
  int dbase = d*DW + lg*4;
  int lq = lg*4;

  int r = r0 + rg;
  for (; r + 384 < r1; r += 512){
    int c0 = tgt[r], c1 = tgt[r+128], c2 = tgt[r+256], c3 = tgt[r+384];
    float4 v0 = *(const float4*)&X[(unsigned)r      *DIM + dbase];
    float4 v1 = *(const float4*)&X[(unsigned)(r+128)*DIM + dbase];
    float4 v2 = *(const float4*)&X[(unsigned)(r+256)*DIM + dbase];
    float4 v3 = *(const float4*)&X[(unsigned)(r+384)*DIM + dbase];
    int b0 = c0<<5, q0 = lq + (c0&31);
    atomicAdd(&acc[b0 + ((q0  )&31)], v0.x);
    atomicAdd(&acc[b0 + ((q0+1)&31)], v0.y);
    atomicAdd(&acc[b0 + ((q0+2)&31)], v0.z);
    atomicAdd(&acc[b0 + ((q0+3)&31)], v0.w);
    int b1 = c1<<5, q1 = lq + (c1&31);
    atomicAdd(&acc[b1 + ((q1  )&31)], v1.x);
    atomicAdd(&acc[b1 + ((q1+1)&31)], v1.y);
    atomicAdd(&acc[b1 + ((q1+2)&31)], v1.z);
    atomicAdd(&acc[b1 + ((q1+3)&31)], v1.w);
    int b2 = c2<<5, q2 = lq + (c2&31);
    atomicAdd(&acc[b2 + ((q2  )&31)], v2.x);
    atomicAdd(&acc[b2 + ((q2+1)&31)], v2.y);
    atomicAdd(&acc[b2 + ((q2+2)&31)], v2.z);
    atomicAdd(&acc[b2 + ((q2+3)&31)], v2.w);
    int b3 = c3<<5, q3 = lq + (c3&31);
    atomicAdd(&acc[b3 + ((q3  )&31)], v3.x);
    atomicAdd(&acc[b3 + ((q3+1)&31)], v3.y);
    atomicAdd(&acc[b3 + ((q3+2)&31)], v3.z);
    atomicAdd(&acc[b3 + ((q3+3)&31)], v3.w);
  }
  for (; r < r1; r += 128){
    int c = tgt[r];
    float4 v = *(const float4*)&X[(unsigned)r*DIM + dbase];
    int b = c<<5, q = lq + (c&31);
    atomicAdd(&acc[b + ((q  )&31)], v.x);
    atomicAdd(&acc[b + ((q+1)&31)], v.y);
    atomicAdd(&acc[b + ((q+2)&31)], v.z);
    atomicAdd(&acc[b + ((q+3)&31)], v.w);
  }
  __syncthreads();

  float* Pblk = P + ((size_t)(a*DSL + d)*S + sl) * (size_t)(NCLS*DW);
  for (int i = tid; i < NCLS*DW; i += 1024){
    int cls = i >> 5, w = i & 31;
    Pblk[i] = acc[(cls<<5) | ((w + cls)&31)];   // un-rotate
  }
}

// ---------------- reduce partials -> centers, sq, colsum, sumsq ---------------
__global__ __launch_bounds__(256) void k_reduce(
    const float* __restrict__ P, const int* __restrict__ counts, int S,
    float* __restrict__ T, float* __restrict__ sq, float* __restrict__ scol,
    double* __restrict__ sumsq)
{
  int c = blockIdx.x;           // class
  int t = threadIdx.x;          // dim 0..255
  int d = t >> 5, w = t & 31;
  size_t stride = (size_t)(NCLS*DW);
  const float* pr = P + (size_t)(0*DSL + d)*S*stride + (size_t)c*DW + w;
  const float* pi = P + (size_t)(1*DSL + d)*S*stride + (size_t)c*DW + w;
  float sr = 0.f, si = 0.f;
  for (int s2 = 0; s2 < S; ++s2){
    sr += pr[(size_t)s2*stride];
    si += pi[(size_t)s2*stride];
  }
  float invd = 1.f / fmaxf((float)counts[c], 1.f);
  float cr = sr*invd, ci = si*invd;
  T[c*DIM + t]        = cr;
  T[(NCLS+c)*DIM + t] = ci;
  atomicAdd(&scol[t], cr + ci);
  float vr = cr*cr, vi = ci*ci;
  #pragma unroll
  for (int o = 32; o > 0; o >>= 1){ vr += __shfl_down(vr,o); vi += __shfl_down(vi,o); }
  __shared__ float redr[4], redi[4];
  int lane = t & 63, wid = t >> 6;
  if (lane == 0){ redr[wid] = vr; redi[wid] = vi; }
  __syncthreads();
  if (t == 0){
    float R = redr[0]+redr[1]+redr[2]+redr[3];
    float I = redi[0]+redi[1]+redi[2]+redi[3];
    sq[c]      = R;
    sq[NCLS+c] = I;
    atomicAdd(sumsq, (double)R + (double)I);
  }
}

// ---------------- closed-form bandwidth ---------------------------------------
// sum(dists) = 2n*sum(sq) - 2*||colsum||^2  (clamp affects only ~1e-6 diagonal noise)
__global__ void k_bw(const float* __restrict__ s, const double* __restrict__ sumsq,
                     float* __restrict__ invbw){
  double ss = 0.0;
  for (int d = 0; d < DIM; ++d){ double v = (double)s[d]; ss += v*v; }
  double S1 = 2.0*(double)NTOT*(*sumsq) - 2.0*ss;
  double bw = S1 / ((double)NTOT*(double)NTOT - (double)NTOT) / 4.0; // / KERNEL_MUL^(KN//2)
  #pragma unroll
  for (int k = 0; k < 5; ++k)
    invbw[k] = (float)(1.0 / (bw * (double)(1 << k)));
}

// ---------------- fused Gram + 5-exp kernel + signed reduction ----------------
__global__ __launch_bounds__(256) void k_mmd(const float* __restrict__ T,
    const float* __restrict__ sq, const float* __restrict__ invbw,
    double* __restrict__ lossacc)
{
  __shared__ float As[64][68];
  __shared__ float Bs[64][68];
  __shared__ float red[4];
  int bx = blockIdx.x, by = blockIdx.y;
  int tid = threadIdx.x;
  int tx = tid & 15, ty = tid >> 4;
  int rowA = by*64, rowB = bx*64;
  float acc[4][4];
  #pragma unroll
  for (int a = 0; a < 4; ++a)
    #pragma unroll
    for (int b = 0; b < 4; ++b) acc[a][b] = 0.f;

  for (int kk = 0; kk < DIM; kk += 64){
    #pragma unroll
    for (int it = 0; it < 4; ++it){
      int idx = it*256 + tid;
      int r = idx >> 4, c4 = idx & 15;
      float4 va = *(const float4*)&T[(rowA + r)*DIM + kk + c4*4];
      float4 vb = *(const float4*)&T[(rowB + r)*DIM + kk + c4*4];
      *(float4*)&As[r][c4*4] = va;
      *(float4*)&Bs[r][c4*4] = vb;
    }
    __syncthreads();
    #pragma unroll 8
    for (int k = 0; k < 64; ++k){
      float a0 = As[ty*4+0][k], a1 = As[ty*4+1][k], a2 = As[ty*4+2][k], a3 = As[ty*4+3][k];
      float b0 = Bs[tx*4+0][k], b1 = Bs[tx*4+1][k], b2 = Bs[tx*4+2][k], b3 = Bs[tx*4+3][k];
      acc[0][0] += a0*b0; acc[0][1] += a0*b1; acc[0][2] += a0*b2; acc[0][3] += a0*b3;
      acc[1][0] += a1*b0; acc[1][1] += a1*b1; acc[1][2] += a1*b2; acc[1][3] += a1*b3;
      acc[2][0] += a2*b0; acc[2][1] += a2*b1; acc[2][2] += a2*b2; acc[2][3] += a2*b3;
      acc[3][0] += a3*b0; acc[3][1] += a3*b1; acc[3][2] += a3*b2; acc[3][3] += a3*b3;
    }
    __syncthreads();
  }

  float i0 = invbw[0], i1 = invbw[1], i2 = invbw[2], i3 = invbw[3], i4 = invbw[4];
  float lacc = 0.f;
  #pragma unroll
  for (int a = 0; a < 4; ++a){
    int i = rowA + ty*4 + a;
    float sqi  = sq[i];
    float sgnI = (i < NCLS) ? 1.f : -1.f;
    #pragma unroll
    for (int b = 0; b < 4; ++b){
      int j = rowB + tx*4 + b;
      float d = sqi + sq[j] - 2.f*acc[a][b];
      d = fmaxf(d, 0.f);
      float w = __expf(-d*i0) + __expf(-d*i1) + __expf(-d*i2) + __expf(-d*i3) + __expf(-d*i4);
      lacc += ((j < NCLS) ? sgnI : -sgnI) * w;
    }
  }
  #pragma unroll
  for (int o = 32; o > 0; o >>= 1) lacc += __shfl_down(lacc, o);
  int lane = tid & 63, wid = tid >> 6;
  if (lane == 0) red[wid] = lacc;
  __syncthreads();
  if (tid == 0) atomicAdd(lossacc, (double)(red[0]+red[1]+red[2]+red[3]));
}

__global__ void k_final(const double* __restrict__ lossacc, float* __restrict__ out){
  out[0] = (float)(*lossacc * (1.0 / ((double)NCLS * (double)NCLS)));
}

extern "C" void kernel_launch(void* const* d_in, const int* in_sizes, int n_in,
                              void* d_out, int out_size, void* d_ws, size_t ws_size,
                              hipStream_t stream) {
  const float* xr  = (const float*)d_in[0];
  const float* xi  = (const float*)d_in[1];
  const int*   tgt = (const int*)d_in[2];
  float* out = (float*)d_out;
  int n = in_sizes[2];                 // 131072 rows

  char* w = (char*)d_ws;
  int* counts   = (int*)w;                      // 1024
  float* T      = (float*)(counts + NCLS);      // 2048*256
  float* sq     = T + NTOT*DIM;                 // 2048
  float* s      = sq + NTOT;                    // 256
  float* invbw  = s + DIM;                      // 5 (+3 pad)
  double* sumsq = (double*)(invbw + 8);         // 1
  double* lossd = sumsq + 1;                    // 1
  float* P      = (float*)(lossd + 1);          // S * 2 MB of partials

  size_t fixed = (size_t)((char*)P - (char*)d_ws);
  size_t slab_bytes = (size_t)2*DSL*NCLS*DW*sizeof(float);  // 2 MB per slab
  int S = (ws_size > fixed) ? (int)((ws_size - fixed) / slab_bytes) : 1;
  if (S > SMAX) S = SMAX;
  if (S < 1) S = 1;
  int rows_per_slab = (n + S - 1) / S;

  k_init<<<1, 1024, 0, stream>>>(counts, s, sumsq, lossd);
  k_hist<<<256, 256, 0, stream>>>(tgt, n, counts);
  k_partial<<<2*DSL*S, 1024, 0, stream>>>(xr, xi, tgt, n, S, rows_per_slab, P);
  k_reduce<<<NCLS, 256, 0, stream>>>(P, counts, S, T, sq, s, sumsq);
  k_bw<<<1, 1, 0, stream>>>(s, sumsq, invbw);
  k_mmd<<<dim3(32, 32), 256, 0, stream>>>(T, sq, invbw, lossd);
  k_final<<<1, 1, 0, stream>>>(lossd, out);
}

// Round 5
// 344.509 us; speedup vs baseline: 1.2854x; 1.2854x over previous
//
#include <hip/hip_runtime.h>

#define NCLS 1024
#define DIM  256
#define NTOT 2048   // 2*NCLS rows in "total"

__device__ __forceinline__ float4 f4add(float4 a, float4 b){
  return make_float4(a.x+b.x, a.y+b.y, a.z+b.z, a.w+b.w);
}

// ---------------- init: zero the accumulators we atomically add into ----------
__global__ void k_init(int* counts, float* scol){
  int t = threadIdx.x;
  if (t < NCLS) counts[t] = 0;
  if (t < DIM)  scol[t] = 0.f;
}

// ---------------- histogram of targets (LDS-staged) ---------------------------
__global__ __launch_bounds__(256) void k_hist(const int* __restrict__ tgt, int n,
                                              int* __restrict__ counts){
  __shared__ int h[NCLS];
  for (int i = threadIdx.x; i < NCLS; i += blockDim.x) h[i] = 0;
  __syncthreads();
  for (int i = blockIdx.x*blockDim.x + threadIdx.x; i < n; i += gridDim.x*blockDim.x)
    atomicAdd(&h[tgt[i]], 1);
  __syncthreads();
  for (int i = threadIdx.x; i < NCLS; i += blockDim.x)
    if (h[i]) atomicAdd(&counts[i], h[i]);
}

// ---------------- exclusive scan over 1024 counts (single block) --------------
__global__ void k_scan(const int* __restrict__ counts, int* __restrict__ offsets,
                       int* __restrict__ cursor){
  __shared__ int buf[NCLS];
  int t = threadIdx.x;
  int v = counts[t];
  buf[t] = v;
  __syncthreads();
  for (int o = 1; o < NCLS; o <<= 1){
    int u = (t >= o) ? buf[t-o] : 0;
    __syncthreads();
    buf[t] += u;
    __syncthreads();
  }
  int excl = buf[t] - v;
  offsets[t] = excl;
  cursor[t]  = excl;
}

// ---------------- counting-sort scatter: per-class row lists ------------------
__global__ __launch_bounds__(256) void k_scatter(const int* __restrict__ tgt, int n,
                                                 int* __restrict__ cursor,
                                                 int* __restrict__ index){
  for (int i = blockIdx.x*blockDim.x + threadIdx.x; i < n; i += gridDim.x*blockDim.x){
    int t = tgt[i];
    int pos = atomicAdd(&cursor[t], 1);
    index[pos] = i;
  }
}

// ---------------- partial gather: 4 blocks per class ---------------------------
// bid = cls*4 + h*2 + a : a selects array (rgb/ir), h selects row-half.
// 4096 blocks x 4 waves, low VGPR -> ~32 waves/CU; TLP supplies the
// memory-level parallelism the compiler refused to give via ILP (R2/R3).
__global__ __launch_bounds__(256) void k_gather(const float* __restrict__ xr,
    const float* __restrict__ xi, const int* __restrict__ index,
    const int* __restrict__ counts, const int* __restrict__ offsets,
    float* __restrict__ Ppart)
{
  int bid = blockIdx.x;
  int cls = bid >> 2;
  int h   = (bid >> 1) & 1;
  int a   = bid & 1;
  int tid = threadIdx.x;
  int l = tid & 63, g = tid >> 6;
  int cnt = counts[cls], off = offsets[cls];
  int c0 = (cnt + 1) >> 1;
  int start = off + (h ? c0 : 0);
  int end   = off + (h ? cnt : c0);
  const float4* __restrict__ X4 = (const float4*)(a ? xi : xr);

  float4 s0 = make_float4(0,0,0,0), s1 = make_float4(0,0,0,0);
  int j = start + g;
  for (; j + 4 < end; j += 8){
    unsigned r0 = (unsigned)index[j];
    unsigned r1 = (unsigned)index[j+4];
    float4 v0 = X4[r0*64u + l];
    float4 v1 = X4[r1*64u + l];
    s0 = f4add(s0, v0);
    s1 = f4add(s1, v1);
  }
  if (j < end) s0 = f4add(s0, X4[(unsigned)index[j]*64u + l]);
  s0 = f4add(s0, s1);

  __shared__ float4 sh[256];
  sh[tid] = s0; __syncthreads();
  if (tid < 64){
    float4 r = f4add(f4add(sh[tid], sh[tid+64]), f4add(sh[tid+128], sh[tid+192]));
    ((float4*)Ppart)[bid*64 + tid] = r;
  }
}

// ---------------- combine partials -> T row, sq, colsum ------------------------
__global__ __launch_bounds__(64) void k_combine(const float* __restrict__ Ppart,
    const int* __restrict__ counts, float* __restrict__ T, float* __restrict__ sq,
    float* __restrict__ scol)
{
  int b = blockIdx.x;            // cls*2 + a
  int cls = b >> 1, a = b & 1;
  int l = threadIdx.x;           // 0..63
  const float4* P4 = (const float4*)Ppart;
  float4 p0 = P4[(cls*4 + 0 + a)*64 + l];
  float4 p1 = P4[(cls*4 + 2 + a)*64 + l];
  float invd = 1.f / fmaxf((float)counts[cls], 1.f);
  float4 c;
  c.x = (p0.x + p1.x) * invd;
  c.y = (p0.y + p1.y) * invd;
  c.z = (p0.z + p1.z) * invd;
  c.w = (p0.w + p1.w) * invd;
  int row = a ? (NCLS + cls) : cls;
  ((float4*)T)[row*64 + l] = c;
  atomicAdd(&scol[l*4+0], c.x);
  atomicAdd(&scol[l*4+1], c.y);
  atomicAdd(&scol[l*4+2], c.z);
  atomicAdd(&scol[l*4+3], c.w);
  float v = c.x*c.x + c.y*c.y + c.z*c.z + c.w*c.w;
  #pragma unroll
  for (int o = 32; o > 0; o >>= 1) v += __shfl_down(v, o);
  if (l == 0) sq[row] = v;
}

// ---------------- bandwidth: parallel reduce of sq + ||colsum||^2 -------------
// sum(dists) = 2n*sum(sq) - 2*||colsum||^2  (clamp affects only ~1e-6 diag noise)
__global__ __launch_bounds__(256) void k_bw(const float* __restrict__ sq,
    const float* __restrict__ scol, float* __restrict__ invbw){
  int t = threadIdx.x;
  double acc = 0.0;
  for (int i = t; i < NTOT; i += 256) acc += (double)sq[i];
  double cs = (double)scol[t];
  double c2 = cs*cs;
  #pragma unroll
  for (int o = 32; o > 0; o >>= 1){
    acc += __shfl_down(acc, o);
    c2  += __shfl_down(c2, o);
  }
  __shared__ double ra[4], rc[4];
  int lane = t & 63, wid = t >> 6;
  if (lane == 0){ ra[wid] = acc; rc[wid] = c2; }
  __syncthreads();
  if (t == 0){
    double S_sq = ra[0]+ra[1]+ra[2]+ra[3];
    double S_cs = rc[0]+rc[1]+rc[2]+rc[3];
    double S1 = 2.0*(double)NTOT*S_sq - 2.0*S_cs;
    double bw = S1 / ((double)NTOT*(double)NTOT - (double)NTOT) / 4.0;
    #pragma unroll
    for (int k = 0; k < 5; ++k)
      invbw[k] = (float)(1.0 / (bw * (double)(1 << k)));
  }
}

// ---------------- fused Gram + 5-exp kernel + signed reduction ----------------
__global__ __launch_bounds__(256) void k_mmd(const float* __restrict__ T,
    const float* __restrict__ sq, const float* __restrict__ invbw,
    double* __restrict__ lossacc)
{
  __shared__ float As[64][68];
  __shared__ float Bs[64][68];
  __shared__ float red[4];
  int bx = blockIdx.x, by = blockIdx.y;
  int tid = threadIdx.x;
  int tx = tid & 15, ty = tid >> 4;
  int rowA = by*64, rowB = bx*64;
  float acc[4][4];
  #pragma unroll
  for (int a = 0; a < 4; ++a)
    #pragma unroll
    for (int b = 0; b < 4; ++b) acc[a][b] = 0.f;

  for (int kk = 0; kk < DIM; kk += 64){
    #pragma unroll
    for (int it = 0; it < 4; ++it){
      int idx = it*256 + tid;
      int r = idx >> 4, c4 = idx & 15;
      float4 va = *(const float4*)&T[(rowA + r)*DIM + kk + c4*4];
      float4 vb = *(const float4*)&T[(rowB + r)*DIM + kk + c4*4];
      *(float4*)&As[r][c4*4] = va;
      *(float4*)&Bs[r][c4*4] = vb;
    }
    __syncthreads();
    #pragma unroll 8
    for (int k = 0; k < 64; ++k){
      float a0 = As[ty*4+0][k], a1 = As[ty*4+1][k], a2 = As[ty*4+2][k], a3 = As[ty*4+3][k];
      float b0 = Bs[tx*4+0][k], b1 = Bs[tx*4+1][k], b2 = Bs[tx*4+2][k], b3 = Bs[tx*4+3][k];
      acc[0][0] += a0*b0; acc[0][1] += a0*b1; acc[0][2] += a0*b2; acc[0][3] += a0*b3;
      acc[1][0] += a1*b0; acc[1][1] += a1*b1; acc[1][2] += a1*b2; acc[1][3] += a1*b3;
      acc[2][0] += a2*b0; acc[2][1] += a2*b1; acc[2][2] += a2*b2; acc[2][3] += a2*b3;
      acc[3][0] += a3*b0; acc[3][1] += a3*b1; acc[3][2] += a3*b2; acc[3][3] += a3*b3;
    }
    __syncthreads();
  }

  float i0 = invbw[0], i1 = invbw[1], i2 = invbw[2], i3 = invbw[3], i4 = invbw[4];
  float lacc = 0.f;
  #pragma unroll
  for (int a = 0; a < 4; ++a){
    int i = rowA + ty*4 + a;
    float sqi  = sq[i];
    float sgnI = (i < NCLS) ? 1.f : -1.f;
    #pragma unroll
    for (int b = 0; b < 4; ++b){
      int j = rowB + tx*4 + b;
      float d = sqi + sq[j] - 2.f*acc[a][b];
      d = fmaxf(d, 0.f);
      float w = __expf(-d*i0) + __expf(-d*i1) + __expf(-d*i2) + __expf(-d*i3) + __expf(-d*i4);
      lacc += ((j < NCLS) ? sgnI : -sgnI) * w;
    }
  }
  #pragma unroll
  for (int o = 32; o > 0; o >>= 1) lacc += __shfl_down(lacc, o);
  int lane = tid & 63, wid = tid >> 6;
  if (lane == 0) red[wid] = lacc;
  __syncthreads();
  if (tid == 0) atomicAdd(lossacc, (double)(red[0]+red[1]+red[2]+red[3]));
}

__global__ void k_zero_loss(double* lossacc){ *lossacc = 0.0; }

__global__ void k_final(const double* __restrict__ lossacc, float* __restrict__ out){
  out[0] = (float)(*lossacc * (1.0 / ((double)NCLS * (double)NCLS)));
}

extern "C" void kernel_launch(void* const* d_in, const int* in_sizes, int n_in,
                              void* d_out, int out_size, void* d_ws, size_t ws_size,
                              hipStream_t stream) {
  const float* xr  = (const float*)d_in[0];
  const float* xi  = (const float*)d_in[1];
  const int*   tgt = (const int*)d_in[2];
  float* out = (float*)d_out;
  int n = in_sizes[2];                 // 131072 rows

  char* w = (char*)d_ws;
  int* counts   = (int*)w;                      // 1024
  int* offsets  = counts + NCLS;                // 1024
  int* cursor   = offsets + NCLS;               // 1024
  int* index    = cursor + NCLS;                // n
  float* T      = (float*)(index + n);          // 2048*256
  float* sq     = T + NTOT*DIM;                 // 2048
  float* scol   = sq + NTOT;                    // 256
  float* invbw  = scol + DIM;                   // 5 (+3 pad)
  double* lossd = (double*)(invbw + 8);         // 1
  float* Ppart  = (float*)(lossd + 1);          // 4096*256 = 4 MB

  k_init<<<1, 1024, 0, stream>>>(counts, scol);
  k_zero_loss<<<1, 1, 0, stream>>>(lossd);
  k_hist<<<256, 256, 0, stream>>>(tgt, n, counts);
  k_scan<<<1, 1024, 0, stream>>>(counts, offsets, cursor);
  k_scatter<<<256, 256, 0, stream>>>(tgt, n, cursor, index);
  k_gather<<<4*NCLS, 256, 0, stream>>>(xr, xi, index, counts, offsets, Ppart);
  k_combine<<<2*NCLS, 64, 0, stream>>>(Ppart, counts, T, sq, scol);
  k_bw<<<1, 256, 0, stream>>>(sq, scol, invbw);
  k_mmd<<<dim3(32, 32), 256, 0, stream>>>(T, sq, invbw, lossd);
  k_final<<<1, 1, 0, stream>>>(lossd, out);
}

// Round 6
// 150.982 us; speedup vs baseline: 2.9331x; 2.2818x over previous
//
#include <hip/hip_runtime.h>

#define NCLS 1024
#define DIM  256
#define NTOT 2048   // 2*NCLS rows in "total"

__device__ __forceinline__ float4 f4add(float4 a, float4 b){
  return make_float4(a.x+b.x, a.y+b.y, a.z+b.z, a.w+b.w);
}

// ---------------- init ---------------------------------------------------------
__global__ void k_init(int* counts, double* lossacc){
  int t = threadIdx.x;
  if (t < NCLS) counts[t] = 0;
  if (t == 0) *lossacc = 0.0;
}

// ---------------- histogram of targets (LDS-staged) ---------------------------
__global__ __launch_bounds__(256) void k_hist(const int* __restrict__ tgt, int n,
                                              int* __restrict__ counts){
  __shared__ int h[NCLS];
  for (int i = threadIdx.x; i < NCLS; i += blockDim.x) h[i] = 0;
  __syncthreads();
  for (int i = blockIdx.x*blockDim.x + threadIdx.x; i < n; i += gridDim.x*blockDim.x)
    atomicAdd(&h[tgt[i]], 1);
  __syncthreads();
  for (int i = threadIdx.x; i < NCLS; i += blockDim.x)
    if (h[i]) atomicAdd(&counts[i], h[i]);
}

// ---------------- exclusive scan over 1024 counts (single block) --------------
__global__ void k_scan(const int* __restrict__ counts, int* __restrict__ offsets,
                       int* __restrict__ cursor){
  __shared__ int buf[NCLS];
  int t = threadIdx.x;
  int v = counts[t];
  buf[t] = v;
  __syncthreads();
  for (int o = 1; o < NCLS; o <<= 1){
    int u = (t >= o) ? buf[t-o] : 0;
    __syncthreads();
    buf[t] += u;
    __syncthreads();
  }
  int excl = buf[t] - v;
  offsets[t] = excl;
  cursor[t]  = excl;
}

// ---------------- counting-sort scatter: per-class row lists ------------------
__global__ __launch_bounds__(256) void k_scatter(const int* __restrict__ tgt, int n,
                                                 int* __restrict__ cursor,
                                                 int* __restrict__ index){
  for (int i = blockIdx.x*blockDim.x + threadIdx.x; i < n; i += gridDim.x*blockDim.x){
    int t = tgt[i];
    int pos = atomicAdd(&cursor[t], 1);
    index[pos] = i;
  }
}

// ---------------- partial gather: 4 blocks per class ---------------------------
// bid = cls*4 + h*2 + a : a selects array (rgb/ir), h selects row-half.
// TLP supplies memory-level parallelism (R2/R3 showed the compiler won't via ILP).
__global__ __launch_bounds__(256) void k_gather(const float* __restrict__ xr,
    const float* __restrict__ xi, const int* __restrict__ index,
    const int* __restrict__ counts, const int* __restrict__ offsets,
    float* __restrict__ Ppart)
{
  int bid = blockIdx.x;
  int cls = bid >> 2;
  int h   = (bid >> 1) & 1;
  int a   = bid & 1;
  int tid = threadIdx.x;
  int l = tid & 63, g = tid >> 6;
  int cnt = counts[cls], off = offsets[cls];
  int c0 = (cnt + 1) >> 1;
  int start = off + (h ? c0 : 0);
  int end   = off + (h ? cnt : c0);
  const float4* __restrict__ X4 = (const float4*)(a ? xi : xr);

  float4 s0 = make_float4(0,0,0,0), s1 = make_float4(0,0,0,0);
  int j = start + g;
  for (; j + 4 < end; j += 8){
    unsigned r0 = (unsigned)index[j];
    unsigned r1 = (unsigned)index[j+4];
    float4 v0 = X4[r0*64u + l];
    float4 v1 = X4[r1*64u + l];
    s0 = f4add(s0, v0);
    s1 = f4add(s1, v1);
  }
  if (j < end) s0 = f4add(s0, X4[(unsigned)index[j]*64u + l]);
  s0 = f4add(s0, s1);

  __shared__ float4 sh[256];
  sh[tid] = s0; __syncthreads();
  if (tid < 64){
    float4 r = f4add(f4add(sh[tid], sh[tid+64]), f4add(sh[tid+128], sh[tid+192]));
    ((float4*)Ppart)[bid*64 + tid] = r;
  }
}

// ---------------- combine partials -> T rows + sq (NO atomics) -----------------
// One wave per (cls, a): 512 blocks x 256 threads.
__global__ __launch_bounds__(256) void k_combine(const float* __restrict__ Ppart,
    const int* __restrict__ counts, float* __restrict__ T, float* __restrict__ sq)
{
  int wv  = blockIdx.x*4 + (threadIdx.x >> 6);   // 0..2047 = cls*2 + a
  int cls = wv >> 1, a = wv & 1;
  int l   = threadIdx.x & 63;
  const float4* P4 = (const float4*)Ppart;
  float4 p0 = P4[(cls*4 + 0 + a)*64 + l];
  float4 p1 = P4[(cls*4 + 2 + a)*64 + l];
  float invd = 1.f / fmaxf((float)counts[cls], 1.f);
  float4 c;
  c.x = (p0.x + p1.x) * invd;
  c.y = (p0.y + p1.y) * invd;
  c.z = (p0.z + p1.z) * invd;
  c.w = (p0.w + p1.w) * invd;
  int row = a ? (NCLS + cls) : cls;
  ((float4*)T)[row*64 + l] = c;
  float v = c.x*c.x + c.y*c.y + c.z*c.z + c.w*c.w;
  #pragma unroll
  for (int o = 32; o > 0; o >>= 1) v += __shfl_down(v, o);
  if (l == 0) sq[row] = v;
}

// ---------------- column-sum partials of T (NO atomics) ------------------------
// 32 blocks; block b sums rows [b*64, b*64+64) -> Pcol[b][256].
__global__ __launch_bounds__(256) void k_colsum(const float* __restrict__ T,
                                                float* __restrict__ Pcol){
  int b = blockIdx.x;
  int tid = threadIdx.x;
  int l = tid & 63, g = tid >> 6;
  const float4* T4 = (const float4*)T;
  float4 acc = make_float4(0,0,0,0);
  for (int r = b*64 + g; r < b*64 + 64; r += 4)
    acc = f4add(acc, T4[r*64 + l]);
  __shared__ float4 sh[256];
  sh[tid] = acc; __syncthreads();
  if (tid < 64){
    float4 r = f4add(f4add(sh[tid], sh[tid+64]), f4add(sh[tid+128], sh[tid+192]));
    ((float4*)Pcol)[b*64 + tid] = r;
  }
}

// ---------------- bandwidth: reduce sq + ||colsum||^2 --------------------------
// sum(dists) = 2n*sum(sq) - 2*||colsum||^2  (clamp affects only ~1e-6 diag noise)
__global__ __launch_bounds__(256) void k_bw(const float* __restrict__ sq,
    const float* __restrict__ Pcol, float* __restrict__ invbw){
  int t = threadIdx.x;
  double acc = 0.0;
  for (int i = t; i < NTOT; i += 256) acc += (double)sq[i];
  float cs = 0.f;
  for (int b = 0; b < 32; ++b) cs += Pcol[b*DIM + t];
  double c2 = (double)cs * (double)cs;
  #pragma unroll
  for (int o = 32; o > 0; o >>= 1){
    acc += __shfl_down(acc, o);
    c2  += __shfl_down(c2, o);
  }
  __shared__ double ra[4], rc[4];
  int lane = t & 63, wid = t >> 6;
  if (lane == 0){ ra[wid] = acc; rc[wid] = c2; }
  __syncthreads();
  if (t == 0){
    double S_sq = ra[0]+ra[1]+ra[2]+ra[3];
    double S_cs = rc[0]+rc[1]+rc[2]+rc[3];
    double S1 = 2.0*(double)NTOT*S_sq - 2.0*S_cs;
    double bw = S1 / ((double)NTOT*(double)NTOT - (double)NTOT) / 4.0;
    #pragma unroll
    for (int k = 0; k < 5; ++k)
      invbw[k] = (float)(1.0 / (bw * (double)(1 << k)));
  }
}

// ---------------- fused Gram + 5-exp kernel + signed reduction ----------------
__global__ __launch_bounds__(256) void k_mmd(const float* __restrict__ T,
    const float* __restrict__ sq, const float* __restrict__ invbw,
    double* __restrict__ lossacc)
{
  __shared__ float As[64][68];
  __shared__ float Bs[64][68];
  __shared__ float red[4];
  int bx = blockIdx.x, by = blockIdx.y;
  int tid = threadIdx.x;
  int tx = tid & 15, ty = tid >> 4;
  int rowA = by*64, rowB = bx*64;
  float acc[4][4];
  #pragma unroll
  for (int a = 0; a < 4; ++a)
    #pragma unroll
    for (int b = 0; b < 4; ++b) acc[a][b] = 0.f;

  for (int kk = 0; kk < DIM; kk += 64){
    #pragma unroll
    for (int it = 0; it < 4; ++it){
      int idx = it*256 + tid;
      int r = idx >> 4, c4 = idx & 15;
      float4 va = *(const float4*)&T[(rowA + r)*DIM + kk + c4*4];
      float4 vb = *(const float4*)&T[(rowB + r)*DIM + kk + c4*4];
      *(float4*)&As[r][c4*4] = va;
      *(float4*)&Bs[r][c4*4] = vb;
    }
    __syncthreads();
    #pragma unroll 8
    for (int k = 0; k < 64; ++k){
      float a0 = As[ty*4+0][k], a1 = As[ty*4+1][k], a2 = As[ty*4+2][k], a3 = As[ty*4+3][k];
      float b0 = Bs[tx*4+0][k], b1 = Bs[tx*4+1][k], b2 = Bs[tx*4+2][k], b3 = Bs[tx*4+3][k];
      acc[0][0] += a0*b0; acc[0][1] += a0*b1; acc[0][2] += a0*b2; acc[0][3] += a0*b3;
      acc[1][0] += a1*b0; acc[1][1] += a1*b1; acc[1][2] += a1*b2; acc[1][3] += a1*b3;
      acc[2][0] += a2*b0; acc[2][1] += a2*b1; acc[2][2] += a2*b2; acc[2][3] += a2*b3;
      acc[3][0] += a3*b0; acc[3][1] += a3*b1; acc[3][2] += a3*b2; acc[3][3] += a3*b3;
    }
    __syncthreads();
  }

  float i0 = invbw[0], i1 = invbw[1], i2 = invbw[2], i3 = invbw[3], i4 = invbw[4];
  float lacc = 0.f;
  #pragma unroll
  for (int a = 0; a < 4; ++a){
    int i = rowA + ty*4 + a;
    float sqi  = sq[i];
    float sgnI = (i < NCLS) ? 1.f : -1.f;
    #pragma unroll
    for (int b = 0; b < 4; ++b){
      int j = rowB + tx*4 + b;
      float d = sqi + sq[j] - 2.f*acc[a][b];
      d = fmaxf(d, 0.f);
      float w = __expf(-d*i0) + __expf(-d*i1) + __expf(-d*i2) + __expf(-d*i3) + __expf(-d*i4);
      lacc += ((j < NCLS) ? sgnI : -sgnI) * w;
    }
  }
  #pragma unroll
  for (int o = 32; o > 0; o >>= 1) lacc += __shfl_down(lacc, o);
  int lane = tid & 63, wid = tid >> 6;
  if (lane == 0) red[wid] = lacc;
  __syncthreads();
  if (tid == 0) atomicAdd(lossacc, (double)(red[0]+red[1]+red[2]+red[3]));
}

__global__ void k_final(const double* __restrict__ lossacc, float* __restrict__ out){
  out[0] = (float)(*lossacc * (1.0 / ((double)NCLS * (double)NCLS)));
}

extern "C" void kernel_launch(void* const* d_in, const int* in_sizes, int n_in,
                              void* d_out, int out_size, void* d_ws, size_t ws_size,
                              hipStream_t stream) {
  const float* xr  = (const float*)d_in[0];
  const float* xi  = (const float*)d_in[1];
  const int*   tgt = (const int*)d_in[2];
  float* out = (float*)d_out;
  int n = in_sizes[2];                 // 131072 rows

  char* w = (char*)d_ws;
  int* counts   = (int*)w;                      // 1024
  int* offsets  = counts + NCLS;                // 1024
  int* cursor   = offsets + NCLS;               // 1024
  int* index    = cursor + NCLS;                // n
  float* T      = (float*)(index + n);          // 2048*256
  float* sq     = T + NTOT*DIM;                 // 2048
  float* invbw  = sq + NTOT;                    // 5 (+3 pad)
  double* lossd = (double*)(invbw + 8);         // 1
  float* Ppart  = (float*)(lossd + 1);          // 4096*256 = 4 MB
  float* Pcol   = Ppart + 4*NCLS*DIM;           // 32*256

  k_init<<<1, 1024, 0, stream>>>(counts, lossd);
  k_hist<<<256, 256, 0, stream>>>(tgt, n, counts);
  k_scan<<<1, 1024, 0, stream>>>(counts, offsets, cursor);
  k_scatter<<<256, 256, 0, stream>>>(tgt, n, cursor, index);
  k_gather<<<4*NCLS, 256, 0, stream>>>(xr, xi, index, counts, offsets, Ppart);
  k_combine<<<NTOT/4, 256, 0, stream>>>(Ppart, counts, T, sq);
  k_colsum<<<32, 256, 0, stream>>>(T, Pcol);
  k_bw<<<1, 256, 0, stream>>>(sq, Pcol, invbw);
  k_mmd<<<dim3(32, 32), 256, 0, stream>>>(T, sq, invbw, lossd);
  k_final<<<1, 1, 0, stream>>>(lossd, out);
}